// Round 1
// baseline (1070.885 us; speedup 1.0000x reference)
//
#include <hip/hip_runtime.h>
#include <math.h>

#define S_LEN 2048
#define E_DIM 1024
#define NHEAD 16
#define HD 64
#define WIN 128
#define NB 2
#define MTOT (NB * S_LEN)   // 4096

// ---------------- GEMM: Y[m,n] = bias[n] + sum_k X[m,k] * W[n,k] ----------------
#define BM 64
#define BN 64
#define BK 32

__global__ __launch_bounds__(256) void gemm_qkv(
    const float* __restrict__ X,
    const float* __restrict__ Wq, const float* __restrict__ bq,
    const float* __restrict__ Wk, const float* __restrict__ bk,
    const float* __restrict__ Wv, const float* __restrict__ bv,
    float* __restrict__ Yq, float* __restrict__ Yk, float* __restrict__ Yv)
{
    const int which = blockIdx.z;
    const float* __restrict__ Wp = (which == 0) ? Wq : ((which == 1) ? Wk : Wv);
    const float* __restrict__ bp = (which == 0) ? bq : ((which == 1) ? bk : bv);
    float* __restrict__ Yp       = (which == 0) ? Yq : ((which == 1) ? Yk : Yv);

    const int m0 = blockIdx.y * BM;
    const int n0 = blockIdx.x * BN;
    const int tid = threadIdx.x;
    const int tx = tid & 15;    // n micro-tile
    const int ty = tid >> 4;    // m micro-tile

    __shared__ __align__(16) float Xs[BK][BM + 4];
    __shared__ __align__(16) float Ws[BK][BN + 4];

    float acc[4][4] = {};

    const int lrow = tid >> 5;  // 0..7
    const int lcol = tid & 31;  // 0..31 (k within chunk)

    for (int k0 = 0; k0 < E_DIM; k0 += BK) {
        #pragma unroll
        for (int s = 0; s < 8; ++s) {
            int row = s * 8 + lrow;
            Xs[lcol][row] = X[(size_t)(m0 + row) * E_DIM + k0 + lcol];
            Ws[lcol][row] = Wp[(size_t)(n0 + row) * E_DIM + k0 + lcol];
        }
        __syncthreads();
        #pragma unroll
        for (int kk = 0; kk < BK; ++kk) {
            float4 A4 = *(const float4*)&Xs[kk][ty * 4];
            float4 B4 = *(const float4*)&Ws[kk][tx * 4];
            const float* ap  = &A4.x;
            const float* bp4 = &B4.x;
            #pragma unroll
            for (int r = 0; r < 4; ++r)
                #pragma unroll
                for (int c = 0; c < 4; ++c)
                    acc[r][c] = fmaf(ap[r], bp4[c], acc[r][c]);
        }
        __syncthreads();
    }
    #pragma unroll
    for (int r = 0; r < 4; ++r) {
        int m = m0 + ty * 4 + r;
        #pragma unroll
        for (int c = 0; c < 4; ++c) {
            int n = n0 + tx * 4 + c;
            Yp[(size_t)m * E_DIM + n] = acc[r][c] + bp[n];
        }
    }
}

// ---------------- V_tot[bh][d] = sum_j V[bh][j][d] ----------------
__global__ __launch_bounds__(256) void vtot_kernel(const float* __restrict__ V,
                                                   float* __restrict__ vt)
{
    int bh = blockIdx.x;
    int d  = threadIdx.x & 63;
    int sl = threadIdx.x >> 6;   // 0..3
    const float* vp = V + (size_t)bh * S_LEN * HD;
    float s = 0.f;
    for (int j = sl * (S_LEN / 4); j < (sl + 1) * (S_LEN / 4); ++j)
        s += vp[(size_t)j * HD + d];
    __shared__ float red[4][64];
    red[sl][d] = s;
    __syncthreads();
    if (sl == 0) vt[bh * HD + d] = red[0][d] + red[1][d] + red[2][d] + red[3][d];
}

// ---------------- windowed attention with zero-padded softmax ----------------
// out[i] = [ sum_win e^{s-m} v_j + e^{-m} (Vtot - Vwin) ] / [ sum_win e^{s-m} + e^{-m} (S - nwin) ]
#define TQ 32
#define TJ 64
#define NCH 5

__global__ __launch_bounds__(256) void attn_kernel(
    const float* __restrict__ Q, const float* __restrict__ K,
    const float* __restrict__ V, const float* __restrict__ vtot,
    float* __restrict__ out)
{
    const int qt = blockIdx.x;   // 0..63
    const int bh = blockIdx.y;   // 0..31
    const int b  = bh >> 4;
    const int h  = bh & 15;
    const int i0 = qt * TQ;
    const int tid = threadIdx.x;
    const int q  = tid >> 3;     // 0..31 query row in tile
    const int g  = tid & 7;      // 0..7 lane group

    __shared__ __align__(16) float qs[TQ][HD + 4];
    __shared__ __align__(16) float ks[TJ][HD + 4];
    __shared__ __align__(16) float vs[TJ][HD + 4];
    __shared__ __align__(16) float sc[TQ][HD + 8];   // probs, ld=72 for bank spread
    __shared__ float redmax[TQ][8];
    __shared__ float redsum[TQ][8];

    const float* __restrict__ Qp = Q + (size_t)bh * S_LEN * HD;
    const float* __restrict__ Kp = K + (size_t)bh * S_LEN * HD;
    const float* __restrict__ Vp = V + (size_t)bh * S_LEN * HD;

    #pragma unroll
    for (int s = 0; s < 8; ++s) {
        int flat = s * 256 + tid;
        int row = flat >> 6, col = flat & 63;
        qs[row][col] = Qp[(size_t)(i0 + row) * HD + col];
    }

    const int i   = i0 + q;
    const int jlo = (i - WIN > 0) ? (i - WIN) : 0;
    const int jhi = (i + WIN < S_LEN) ? (i + WIN) : S_LEN;  // exclusive

    float m_run = -INFINITY;
    float l_run = 0.f;
    float acc0[4] = {0.f, 0.f, 0.f, 0.f};  // d = g*4 + dd
    float acc1[4] = {0.f, 0.f, 0.f, 0.f};  // d = 32 + g*4 + dd
    float vw0[4]  = {0.f, 0.f, 0.f, 0.f};
    float vw1[4]  = {0.f, 0.f, 0.f, 0.f};

    for (int c = 0; c < NCH; ++c) {
        const int jc0 = i0 - WIN + c * TJ;
        // stage K,V chunk (zero-fill out of [0,S))
        #pragma unroll
        for (int s = 0; s < 16; ++s) {
            int flat = s * 256 + tid;
            int row = flat >> 6, col = flat & 63;
            int jg = jc0 + row;
            bool ok = (jg >= 0) && (jg < S_LEN);
            size_t off = (size_t)(ok ? jg : 0) * HD + col;
            ks[row][col] = ok ? Kp[off] : 0.f;
            vs[row][col] = ok ? Vp[off] : 0.f;
        }
        __syncthreads();

        // scores: this thread covers row q, keys j = jj*8 + g (strided to avoid bank conflicts)
        float sv[8];
        #pragma unroll
        for (int jj = 0; jj < 8; ++jj) sv[jj] = 0.f;
        #pragma unroll
        for (int db = 0; db < 16; ++db) {
            float4 qv = *(const float4*)&qs[q][db * 4];
            #pragma unroll
            for (int jj = 0; jj < 8; ++jj) {
                float4 kv = *(const float4*)&ks[jj * 8 + g][db * 4];
                sv[jj] = fmaf(qv.x, kv.x, sv[jj]);
                sv[jj] = fmaf(qv.y, kv.y, sv[jj]);
                sv[jj] = fmaf(qv.z, kv.z, sv[jj]);
                sv[jj] = fmaf(qv.w, kv.w, sv[jj]);
            }
        }
        float cmax = -INFINITY;
        #pragma unroll
        for (int jj = 0; jj < 8; ++jj) {
            int jg = jc0 + jj * 8 + g;
            bool valid = (jg >= jlo) && (jg < jhi);
            sv[jj] = valid ? sv[jj] * 0.125f : -INFINITY;
            cmax = fmaxf(cmax, sv[jj]);
        }
        redmax[q][g] = cmax;
        __syncthreads();
        float chmax = redmax[q][0];
        #pragma unroll
        for (int t = 1; t < 8; ++t) chmax = fmaxf(chmax, redmax[q][t]);
        float m_new = fmaxf(m_run, chmax);
        float alpha, psum = 0.f;
        if (m_new == -INFINITY) {
            // no valid key seen yet for this row in any chunk so far
            alpha = 1.f;
            #pragma unroll
            for (int jj = 0; jj < 8; ++jj) sc[q][jj * 8 + g] = 0.f;
        } else {
            alpha = __expf(m_run - m_new);   // m_run=-inf -> 0, correct
            #pragma unroll
            for (int jj = 0; jj < 8; ++jj) {
                float p = (sv[jj] == -INFINITY) ? 0.f : __expf(sv[jj] - m_new);
                sc[q][jj * 8 + g] = p;
                psum += p;
            }
        }
        redsum[q][g] = psum;
        __syncthreads();
        float csum = 0.f;
        #pragma unroll
        for (int t = 0; t < 8; ++t) csum += redsum[q][t];
        l_run = l_run * alpha + csum;
        m_run = m_new;

        #pragma unroll
        for (int dd = 0; dd < 4; ++dd) { acc0[dd] *= alpha; acc1[dd] *= alpha; }

        #pragma unroll 8
        for (int j = 0; j < TJ; ++j) {
            float p = sc[q][j];
            int jg = jc0 + j;
            float w = ((jg >= jlo) && (jg < jhi)) ? 1.f : 0.f;
            float4 va = *(const float4*)&vs[j][g * 4];
            float4 vb = *(const float4*)&vs[j][32 + g * 4];
            const float* pa = &va.x;
            const float* pb = &vb.x;
            #pragma unroll
            for (int dd = 0; dd < 4; ++dd) {
                acc0[dd] = fmaf(p, pa[dd], acc0[dd]);
                acc1[dd] = fmaf(p, pb[dd], acc1[dd]);
                vw0[dd]  = fmaf(w, pa[dd], vw0[dd]);
                vw1[dd]  = fmaf(w, pb[dd], vw1[dd]);
            }
        }
        __syncthreads();
    }

    // finalize with the zero-class (out-of-window scores are exactly 0 pre-softmax)
    float m_fin = fmaxf(m_run, 0.f);
    float es = (m_run == -INFINITY) ? 0.f : __expf(m_run - m_fin);
    float ez = __expf(-m_fin);
    int nwin = jhi - jlo;
    float l_fin = l_run * es + ez * (float)(S_LEN - nwin);
    float inv = 1.f / l_fin;
    const float* vt = vtot + bh * HD;
    float* op = out + ((size_t)(b * S_LEN + i) * NHEAD + h) * HD;
    #pragma unroll
    for (int dd = 0; dd < 4; ++dd) {
        int d0 = g * 4 + dd;
        int d1 = 32 + g * 4 + dd;
        op[d0] = (acc0[dd] * es + ez * (vt[d0] - vw0[dd])) * inv;
        op[d1] = (acc1[dd] * es + ez * (vt[d1] - vw1[dd])) * inv;
    }
}

extern "C" void kernel_launch(void* const* d_in, const int* in_sizes, int n_in,
                              void* d_out, int out_size, void* d_ws, size_t ws_size,
                              hipStream_t stream)
{
    const float* x  = (const float*)d_in[0];
    const float* Wq = (const float*)d_in[1];
    const float* bq = (const float*)d_in[2];
    const float* Wk = (const float*)d_in[3];
    const float* bk = (const float*)d_in[4];
    const float* Wv = (const float*)d_in[5];
    const float* bv = (const float*)d_in[6];
    float* out = (float*)d_out;
    float* ws  = (float*)d_ws;

    const size_t NBSE = (size_t)NB * S_LEN * E_DIM;  // 4194304 floats per buffer
    float* Yq = ws;
    float* Yk = ws + NBSE;
    float* Yv = ws + 2 * NBSE;
    float* vt = ws + 3 * NBSE;

    dim3 gg(E_DIM / BN, MTOT / BM, 3);
    gemm_qkv<<<gg, 256, 0, stream>>>(x, Wq, bq, Wk, bk, Wv, bv, Yq, Yk, Yv);
    vtot_kernel<<<NB * NHEAD, 256, 0, stream>>>(Yv, vt);
    attn_kernel<<<dim3(S_LEN / TQ, NB * NHEAD), 256, 0, stream>>>(Yq, Yk, Yv, vt, out);
}

// Round 2
// 284.012 us; speedup vs baseline: 3.7706x; 3.7706x over previous
//
#include <hip/hip_runtime.h>
#include <math.h>

#define S_LEN 2048
#define E_DIM 1024
#define NHEAD 16
#define HD 64
#define WIN 128
#define NB 2
#define MTOT (NB * S_LEN)   // 4096
#define NMAT 3072

typedef float f32x4 __attribute__((ext_vector_type(4)));
typedef short bf16x8 __attribute__((ext_vector_type(8)));

#define GLOAD_LDS(g, l) __builtin_amdgcn_global_load_lds( \
    (const __attribute__((address_space(1))) unsigned int*)(g), \
    (__attribute__((address_space(3))) unsigned int*)(l), 16, 0, 0)

__device__ __forceinline__ unsigned short f2bf(float f) {
    unsigned u = __float_as_uint(f);
    u += 0x7fffu + ((u >> 16) & 1u);   // RNE
    return (unsigned short)(u >> 16);
}

// ---------------- fp32 -> bf16 conversion of x and concat(Wq,Wk,Wv) ----------------
__global__ __launch_bounds__(256) void convert_kernel(
    const float* __restrict__ x, const float* __restrict__ wq,
    const float* __restrict__ wk, const float* __restrict__ wv,
    unsigned short* __restrict__ xb, unsigned short* __restrict__ wb)
{
    const int NXQ = MTOT * E_DIM / 4;      // 1048576 quads
    const int NWQ = E_DIM * E_DIM / 4;     // 262144
    const int TOT = NXQ + 3 * NWQ;         // 1835008
    for (int i = blockIdx.x * 256 + threadIdx.x; i < TOT; i += gridDim.x * 256) {
        const float* src; unsigned short* dst; int off;
        if (i < NXQ)               { src = x;  dst = xb;                     off = i; }
        else if (i < NXQ + NWQ)    { src = wq; dst = wb;                     off = i - NXQ; }
        else if (i < NXQ + 2*NWQ)  { src = wk; dst = wb + E_DIM * E_DIM;     off = i - NXQ - NWQ; }
        else                       { src = wv; dst = wb + 2 * E_DIM * E_DIM; off = i - NXQ - 2*NWQ; }
        float4 v = ((const float4*)src)[off];
        ushort4 o;
        o.x = f2bf(v.x); o.y = f2bf(v.y); o.z = f2bf(v.z); o.w = f2bf(v.w);
        ((ushort4*)dst)[off] = o;
    }
}

// ---------------- bf16 MFMA GEMM: Y[m,n] = bias[n] + sum_k A[m,k]*B[n,k] ----------------
// A: [4096][1024] bf16, B: [3072][1024] bf16 (concat Wq,Wk,Wv rows). Output fp32 split.
__global__ __launch_bounds__(256) void gemm_mfma(
    const unsigned short* __restrict__ Ab, const unsigned short* __restrict__ Bb,
    const float* __restrict__ bq, const float* __restrict__ bk, const float* __restrict__ bv,
    float* __restrict__ Yq, float* __restrict__ Yk, float* __restrict__ Yv)
{
    __shared__ __align__(256) unsigned short As[128 * 64];
    __shared__ __align__(256) unsigned short Bs[128 * 64];
    const int tid  = threadIdx.x;
    const int lane = tid & 63;
    const int w    = tid >> 6;
    const int wm   = w & 1, wn = w >> 1;
    const int m0   = blockIdx.y * 128;
    const int n0   = blockIdx.x * 128;
    const int l15  = lane & 15, l4 = lane >> 4;

    f32x4 acc[16] = {};

    for (int k0 = 0; k0 < E_DIM; k0 += 64) {
        #pragma unroll
        for (int is = 0; is < 4; ++is) {
            int gid = is * 256 + tid;
            int r = gid >> 3, sl = gid & 7;
            int gran = sl ^ (r & 7);             // XOR swizzle (granule = 8 bf16 = 16 B)
            int wbs = is * 256 + (tid & 192);    // wave-uniform LDS base (granules)
            GLOAD_LDS(Ab + (size_t)(m0 + r) * E_DIM + k0 + gran * 8, As + wbs * 8);
            GLOAD_LDS(Bb + (size_t)(n0 + r) * E_DIM + k0 + gran * 8, Bs + wbs * 8);
        }
        __syncthreads();
        #pragma unroll
        for (int kk = 0; kk < 2; ++kk) {
            bf16x8 af[4], bfr[4];
            int sa = (kk * 4 + l4) ^ (l15 & 7);
            #pragma unroll
            for (int t = 0; t < 4; ++t) {
                int ra = wm * 64 + t * 16 + l15;  // A row (m), row&7 == l15&7
                af[t]  = *(const bf16x8*)&As[ra * 64 + sa * 8];
                int rb = wn * 64 + t * 16 + l15;  // B row (n)
                bfr[t] = *(const bf16x8*)&Bs[rb * 64 + sa * 8];
            }
            #pragma unroll
            for (int mt = 0; mt < 4; ++mt)
                #pragma unroll
                for (int nt = 0; nt < 4; ++nt)
                    acc[mt * 4 + nt] = __builtin_amdgcn_mfma_f32_16x16x32_bf16(
                        af[mt], bfr[nt], acc[mt * 4 + nt], 0, 0, 0);
        }
        __syncthreads();
    }

    const int sel = n0 >> 10;
    const float* bias = (sel == 0) ? bq : ((sel == 1) ? bk : bv);
    float* Y          = (sel == 0) ? Yq : ((sel == 1) ? Yk : Yv);
    const int nbase = (n0 & 1023) + wn * 64;
    #pragma unroll
    for (int mt = 0; mt < 4; ++mt) {
        #pragma unroll
        for (int nt = 0; nt < 4; ++nt) {
            int n = nbase + nt * 16 + l15;
            float bb = bias[n];
            #pragma unroll
            for (int r = 0; r < 4; ++r) {
                int m = m0 + wm * 64 + mt * 16 + l4 * 4 + r;  // C/D: row=(lane>>4)*4+reg
                Y[(size_t)m * E_DIM + n] = acc[mt * 4 + nt][r] + bb;
            }
        }
    }
}

// ---------------- prefix sums of V along j: P[bh][j][d] = sum_{t<j} V[bh][t][d] ----------------
#define SEG 256
__global__ __launch_bounds__(64) void prefix1(const float* __restrict__ V, float* __restrict__ segsum)
{
    int bh = blockIdx.x, sg = blockIdx.y, d = threadIdx.x;
    const float* vp = V + ((size_t)bh * S_LEN + sg * SEG) * HD + d;
    float s = 0.f;
    for (int j = 0; j < SEG; ++j) s += vp[(size_t)j * HD];
    segsum[(bh * 8 + sg) * HD + d] = s;
}

__global__ __launch_bounds__(64) void prefix2(const float* __restrict__ V,
                                              const float* __restrict__ segsum,
                                              float* __restrict__ P)
{
    int bh = blockIdx.x, sg = blockIdx.y, d = threadIdx.x;
    float off = 0.f;
    for (int t = 0; t < sg; ++t) off += segsum[(bh * 8 + t) * HD + d];
    const float* vp = V + ((size_t)bh * S_LEN + sg * SEG) * HD + d;
    float* pp = P + ((size_t)bh * (S_LEN + 1) + sg * SEG) * HD + d;
    float run = off;
    for (int j = 0; j < SEG; ++j) {
        pp[(size_t)j * HD] = run;
        run += vp[(size_t)j * HD];
    }
    if (sg == 7) pp[(size_t)SEG * HD] = run;   // P[2048]
}

// ---------------- windowed attention, zero-padded softmax, no-max online form ----------------
// out[i] = [ sum_win e^{s} v + (P[S]-P[jhi]+P[jlo]) ] / [ sum_win e^{s} + (S - nwin) ]
__global__ __launch_bounds__(256) void attn2(
    const float* __restrict__ Q, const float* __restrict__ K,
    const float* __restrict__ V, const float* __restrict__ P,
    float* __restrict__ out)
{
    __shared__ __align__(256) float ks[64 * 64];       // swizzled, single buffer
    __shared__ __align__(256) float vs[2][64 * 64];    // swizzled, double buffer
    __shared__ __align__(16)  float qs[32][68];
    __shared__ __align__(16)  float sc[32][72];
    __shared__ float redsum[32][8];

    const int qt = blockIdx.x, bh = blockIdx.y;
    const int b = bh >> 4, h = bh & 15;
    const int i0 = qt * 32;
    const int tid = threadIdx.x;
    const int q = tid >> 3, g = tid & 7;
    const float* Qp = Q + (size_t)bh * S_LEN * HD;
    const float* Kp = K + (size_t)bh * S_LEN * HD;
    const float* Vp = V + (size_t)bh * S_LEN * HD;

    #pragma unroll
    for (int s = 0; s < 8; ++s) {
        int flat = s * 256 + tid;
        int row = flat >> 6, col = flat & 63;
        qs[row][col] = Qp[(size_t)(i0 + row) * HD + col];
    }
    // stage K,V chunk 0 (granule-XOR swizzle; granule = 4 floats = 16 B, 16/row)
    #pragma unroll
    for (int is = 0; is < 4; ++is) {
        int gid = is * 256 + tid;
        int r = gid >> 4, sl = gid & 15;
        int jg = i0 - WIN + r; jg = jg < 0 ? 0 : (jg >= S_LEN ? S_LEN - 1 : jg);
        int gran = sl ^ (r & 15);
        int wbs = is * 256 + (tid & 192);
        GLOAD_LDS(Kp + (size_t)jg * HD + gran * 4, ks + wbs * 4);
        GLOAD_LDS(Vp + (size_t)jg * HD + gran * 4, &vs[0][0] + wbs * 4);
    }
    __syncthreads();

    const int i = i0 + q;
    const int jlo = (i - WIN > 0) ? i - WIN : 0;
    const int jhi = (i + WIN < S_LEN) ? i + WIN : S_LEN;
    float dsum = 0.f;
    float a0x=0.f,a0y=0.f,a0z=0.f,a0w=0.f, a1x=0.f,a1y=0.f,a1z=0.f,a1w=0.f;

    for (int c = 0; c < 5; ++c) {
        const int cb = c & 1;
        const int jc0 = i0 - WIN + c * 64;

        // ---- scores: thread (q,g) covers j = jj*8+g ----
        float sv[8] = {0,0,0,0,0,0,0,0};
        #pragma unroll
        for (int db = 0; db < 16; ++db) {
            float4 qv = *(const float4*)&qs[q][db * 4];
            #pragma unroll
            for (int jj = 0; jj < 8; ++jj) {
                int j = jj * 8 + g;
                float4 kv = *(const float4*)&ks[j * 64 + ((db ^ (j & 15)) * 4)];
                sv[jj] = fmaf(qv.x, kv.x, sv[jj]);
                sv[jj] = fmaf(qv.y, kv.y, sv[jj]);
                sv[jj] = fmaf(qv.z, kv.z, sv[jj]);
                sv[jj] = fmaf(qv.w, kv.w, sv[jj]);
            }
        }
        #pragma unroll
        for (int jj = 0; jj < 8; ++jj) {
            int j = jj * 8 + g;
            int jg = jc0 + j;
            bool valid = (jg >= jlo) && (jg < jhi);
            float p = valid ? __expf(sv[jj] * 0.125f) : 0.f;
            sc[q][j] = p;
            dsum += p;
        }
        __syncthreads();   // B1: probs visible, ks reads of chunk c done

        if (c < 4) {       // overlap next-chunk staging with PV below
            const int jn0 = jc0 + 64;
            #pragma unroll
            for (int is = 0; is < 4; ++is) {
                int gid = is * 256 + tid;
                int r = gid >> 4, sl = gid & 15;
                int jg = jn0 + r; jg = jg < 0 ? 0 : (jg >= S_LEN ? S_LEN - 1 : jg);
                int gran = sl ^ (r & 15);
                int wbs = is * 256 + (tid & 192);
                GLOAD_LDS(Kp + (size_t)jg * HD + gran * 4, ks + wbs * 4);
                GLOAD_LDS(Vp + (size_t)jg * HD + gran * 4, &vs[1 - cb][0] + wbs * 4);
            }
        }

        // ---- PV: thread (q,g) owns d = g*4+dd and 32+g*4+dd ----
        const float* vb = &vs[cb][0];
        #pragma unroll 8
        for (int j = 0; j < 64; ++j) {
            float p = sc[q][j];
            int key = j & 15;
            float4 va = *(const float4*)&vb[j * 64 + ((g ^ key) * 4)];
            float4 vc = *(const float4*)&vb[j * 64 + (((8 + g) ^ key) * 4)];
            a0x = fmaf(p, va.x, a0x); a0y = fmaf(p, va.y, a0y);
            a0z = fmaf(p, va.z, a0z); a0w = fmaf(p, va.w, a0w);
            a1x = fmaf(p, vc.x, a1x); a1y = fmaf(p, vc.y, a1y);
            a1z = fmaf(p, vc.z, a1z); a1w = fmaf(p, vc.w, a1w);
        }
        __syncthreads();   // B2: drains staging (vmcnt) + sc/vs reads done
    }

    redsum[q][g] = dsum;
    __syncthreads();
    float l = 0.f;
    #pragma unroll
    for (int t = 0; t < 8; ++t) l += redsum[q][t];
    const float denom = l + (float)(S_LEN - (jhi - jlo));
    const float inv = 1.f / denom;

    const float* Pp = P + (size_t)bh * (S_LEN + 1) * HD;
    float4 t0  = ((const float4*)&Pp[(size_t)S_LEN * HD])[g];
    float4 t1  = ((const float4*)&Pp[(size_t)S_LEN * HD])[8 + g];
    float4 hi0 = ((const float4*)&Pp[(size_t)jhi * HD])[g];
    float4 hi1 = ((const float4*)&Pp[(size_t)jhi * HD])[8 + g];
    float4 lo0 = ((const float4*)&Pp[(size_t)jlo * HD])[g];
    float4 lo1 = ((const float4*)&Pp[(size_t)jlo * HD])[8 + g];

    float* op = out + ((size_t)(b * S_LEN + i) * NHEAD + h) * HD;
    float4 o0, o1;
    o0.x = (a0x + t0.x - hi0.x + lo0.x) * inv;
    o0.y = (a0y + t0.y - hi0.y + lo0.y) * inv;
    o0.z = (a0z + t0.z - hi0.z + lo0.z) * inv;
    o0.w = (a0w + t0.w - hi0.w + lo0.w) * inv;
    o1.x = (a1x + t1.x - hi1.x + lo1.x) * inv;
    o1.y = (a1y + t1.y - hi1.y + lo1.y) * inv;
    o1.z = (a1z + t1.z - hi1.z + lo1.z) * inv;
    o1.w = (a1w + t1.w - hi1.w + lo1.w) * inv;
    ((float4*)op)[g] = o0;
    ((float4*)op)[8 + g] = o1;
}

extern "C" void kernel_launch(void* const* d_in, const int* in_sizes, int n_in,
                              void* d_out, int out_size, void* d_ws, size_t ws_size,
                              hipStream_t stream)
{
    const float* x  = (const float*)d_in[0];
    const float* Wq = (const float*)d_in[1];
    const float* bq = (const float*)d_in[2];
    const float* Wk = (const float*)d_in[3];
    const float* bk = (const float*)d_in[4];
    const float* Wv = (const float*)d_in[5];
    const float* bv = (const float*)d_in[6];
    float* out = (float*)d_out;
    float* ws  = (float*)d_ws;

    const size_t NY = (size_t)MTOT * E_DIM;              // 4194304
    float* Yq = ws;
    float* Yk = ws + NY;
    float* Yv = ws + 2 * NY;
    float* Pf = ws + 3 * NY;                             // 32*2049*64 = 4196352 floats
    float* seg = ws + 3 * NY + (size_t)32 * (S_LEN + 1) * HD;
    // bf16 staging aliases the P region (P is written only after GEMM consumes these)
    unsigned short* xb = (unsigned short*)Pf;            // 4194304 bf16
    unsigned short* wb = xb + NY;                        // 3145728 bf16

    convert_kernel<<<1792, 256, 0, stream>>>(x, Wq, Wk, Wv, xb, wb);
    gemm_mfma<<<dim3(NMAT / 128, MTOT / 128), 256, 0, stream>>>(xb, wb, bq, bk, bv, Yq, Yk, Yv);
    prefix1<<<dim3(32, 8), 64, 0, stream>>>(Yv, seg);
    prefix2<<<dim3(32, 8), 64, 0, stream>>>(Yv, seg, Pf);
    attn2<<<dim3(S_LEN / 32, NB * NHEAD), 256, 0, stream>>>(Yq, Yk, Yv, Pf, out);
}

// Round 4
// 160.575 us; speedup vs baseline: 6.6691x; 1.7687x over previous
//
#include <hip/hip_runtime.h>
#include <math.h>

#define S_LEN 2048
#define E_DIM 1024
#define NHEAD 16
#define HD 64
#define WIN 128
#define NB 2
#define MTOT (NB * S_LEN)   // 4096
#define NMAT 3072

typedef float f32x4 __attribute__((ext_vector_type(4)));
typedef short bf16x8 __attribute__((ext_vector_type(8)));

#define GLOAD_LDS(g, l) __builtin_amdgcn_global_load_lds( \
    (const __attribute__((address_space(1))) unsigned int*)(g), \
    (__attribute__((address_space(3))) unsigned int*)(l), 16, 0, 0)

__device__ __forceinline__ unsigned short f2bf(float f) {
    unsigned u = __float_as_uint(f);
    u += 0x7fffu + ((u >> 16) & 1u);   // RNE
    return (unsigned short)(u >> 16);
}
__device__ __forceinline__ float bf2f(unsigned short u) {
    return __uint_as_float(((unsigned)u) << 16);
}

// ---------------- fp32 -> bf16 conversion of x and concat(Wq,Wk,Wv) ----------------
__global__ __launch_bounds__(256) void convert_kernel(
    const float* __restrict__ x, const float* __restrict__ wq,
    const float* __restrict__ wk, const float* __restrict__ wv,
    unsigned short* __restrict__ xb, unsigned short* __restrict__ wb)
{
    const int NXQ = MTOT * E_DIM / 4;      // 1048576 quads
    const int NWQ = E_DIM * E_DIM / 4;     // 262144
    const int TOT = NXQ + 3 * NWQ;         // 1835008
    for (int i = blockIdx.x * 256 + threadIdx.x; i < TOT; i += gridDim.x * 256) {
        const float* src; unsigned short* dst; int off;
        if (i < NXQ)               { src = x;  dst = xb;                     off = i; }
        else if (i < NXQ + NWQ)    { src = wq; dst = wb;                     off = i - NXQ; }
        else if (i < NXQ + 2*NWQ)  { src = wk; dst = wb + E_DIM * E_DIM;     off = i - NXQ - NWQ; }
        else                       { src = wv; dst = wb + 2 * E_DIM * E_DIM; off = i - NXQ - 2*NWQ; }
        float4 v = ((const float4*)src)[off];
        ushort4 o;
        o.x = f2bf(v.x); o.y = f2bf(v.y); o.z = f2bf(v.z); o.w = f2bf(v.w);
        ((ushort4*)dst)[off] = o;
    }
}

// ---------------- bf16 MFMA GEMM: Y[m,n] = bias[n] + sum_k A[m,k]*B[n,k] ----------------
// Epilogue stores Q/K/V in the FAITHFUL reshape layout [bh][i][d]:
//   h = (m&2047)>>7, i = ((m&2047)&127)*16 + (n>>6), d = n&63   (reference view() w/o transpose)
__global__ __launch_bounds__(256) void gemm_mfma(
    const unsigned short* __restrict__ Ab, const unsigned short* __restrict__ Bb,
    const float* __restrict__ bq, const float* __restrict__ bk, const float* __restrict__ bv,
    unsigned short* __restrict__ Qb, unsigned short* __restrict__ Kb,
    unsigned short* __restrict__ Vb)
{
    __shared__ __align__(256) unsigned short As[128 * 64];
    __shared__ __align__(256) unsigned short Bs[128 * 64];
    const int tid  = threadIdx.x;
    const int lane = tid & 63;
    const int w    = tid >> 6;
    const int wm   = w & 1, wn = w >> 1;
    const int m0   = blockIdx.y * 128;
    const int n0   = blockIdx.x * 128;
    const int l15  = lane & 15, l4 = lane >> 4;

    f32x4 acc[16] = {};

    for (int k0 = 0; k0 < E_DIM; k0 += 64) {
        #pragma unroll
        for (int is = 0; is < 4; ++is) {
            int gid = is * 256 + tid;
            int r = gid >> 3, sl = gid & 7;
            int gran = sl ^ (r & 7);             // XOR swizzle (granule = 8 bf16 = 16 B)
            int wbs = is * 256 + (tid & 192);    // wave-uniform LDS base (granules)
            GLOAD_LDS(Ab + (size_t)(m0 + r) * E_DIM + k0 + gran * 8, As + wbs * 8);
            GLOAD_LDS(Bb + (size_t)(n0 + r) * E_DIM + k0 + gran * 8, Bs + wbs * 8);
        }
        __syncthreads();
        #pragma unroll
        for (int kk = 0; kk < 2; ++kk) {
            bf16x8 af[4], bfr[4];
            int sa = (kk * 4 + l4) ^ (l15 & 7);
            #pragma unroll
            for (int t = 0; t < 4; ++t) {
                int ra = wm * 64 + t * 16 + l15;
                af[t]  = *(const bf16x8*)&As[ra * 64 + sa * 8];
                int rb = wn * 64 + t * 16 + l15;
                bfr[t] = *(const bf16x8*)&Bs[rb * 64 + sa * 8];
            }
            #pragma unroll
            for (int mt = 0; mt < 4; ++mt)
                #pragma unroll
                for (int nt = 0; nt < 4; ++nt)
                    acc[mt * 4 + nt] = __builtin_amdgcn_mfma_f32_16x16x32_bf16(
                        af[mt], bfr[nt], acc[mt * 4 + nt], 0, 0, 0);
        }
        __syncthreads();
    }

    const int sel = n0 >> 10;
    const float* bias = (sel == 0) ? bq : ((sel == 1) ? bk : bv);
    unsigned short* Yb = (sel == 0) ? Qb : ((sel == 1) ? Kb : Vb);
    const int nbase = (n0 & 1023) + wn * 64;
    #pragma unroll
    for (int mt = 0; mt < 4; ++mt) {
        #pragma unroll
        for (int nt = 0; nt < 4; ++nt) {
            int n = nbase + nt * 16 + l15;      // e index in [0,1024)
            int c = n >> 6, d = n & 63;
            float bb = bias[n];
            #pragma unroll
            for (int r = 0; r < 4; ++r) {
                int m = m0 + wm * 64 + mt * 16 + l4 * 4 + r;
                int b = m >> 11, s = m & 2047;
                int h = s >> 7;
                int i = ((s & 127) << 4) + c;   // faithful reshape
                Yb[(((size_t)(b * 16 + h) * S_LEN + i) << 6) + d] =
                    f2bf(acc[mt * 4 + nt][r] + bb);
            }
        }
    }
}

// ---------------- transpose: Vb[bh][i][d] -> VTb[bh][d][i] ----------------
__global__ __launch_bounds__(256) void transpose_v(
    const unsigned short* __restrict__ Vb, unsigned short* __restrict__ VTb)
{
    __shared__ unsigned short t[64][72];
    const int bh = blockIdx.y;
    const int it0 = blockIdx.x * 64;
    const int tid = threadIdx.x;
    const unsigned short* src = Vb + ((size_t)bh * S_LEN + it0) * HD;
    {
        int r = tid >> 2, c0 = (tid & 3) * 16;
        #pragma unroll
        for (int k = 0; k < 4; ++k) {
            ushort4 a = *(const ushort4*)&src[r * 64 + c0 + k * 4];
            *(ushort4*)&t[r][c0 + k * 4] = a;
        }
    }
    __syncthreads();
    {
        int d = tid >> 2, seg = (tid & 3) * 16;
        unsigned short v[16];
        #pragma unroll
        for (int k = 0; k < 16; ++k) v[k] = t[seg + k][d];
        unsigned short* dst = VTb + ((size_t)bh * HD + d) * S_LEN + it0 + seg;
        #pragma unroll
        for (int k = 0; k < 4; ++k)
            *(ushort4*)&dst[k * 4] = *(const ushort4*)&v[k * 4];
    }
}

// ---------------- vtot[bh][d] = sum_j V[j][d] from VTb (fp32 accumulate) ----------------
__global__ __launch_bounds__(256) void vtot_kernel(const unsigned short* __restrict__ VTb,
                                                   float* __restrict__ vt)
{
    int bh = blockIdx.x;
    int d = threadIdx.x >> 2, part = threadIdx.x & 3;
    const unsigned short* p = VTb + ((size_t)bh * HD + d) * S_LEN + part * 512;
    float s = 0.f;
    for (int it = 0; it < 128; ++it) {
        ushort4 a = ((const ushort4*)p)[it];
        s += bf2f(a.x) + bf2f(a.y) + bf2f(a.z) + bf2f(a.w);
    }
    __shared__ float red[64][4];
    red[d][part] = s;
    __syncthreads();
    if (part == 0) vt[bh * HD + d] = red[d][0] + red[d][1] + red[d][2] + red[d][3];
}

// ---------------- MFMA attention: p'' = win ? e^{s*scale}-1 : 0 ----------------
// out = (sum p'' v + Vtot) / (sum p'' + S)
__global__ __launch_bounds__(256) void attn_mfma(
    const unsigned short* __restrict__ Qb, const unsigned short* __restrict__ Kb,
    const unsigned short* __restrict__ VTb, const float* __restrict__ vtot,
    float* __restrict__ out)
{
    __shared__ __align__(256) unsigned short qs[64 * 64];
    __shared__ __align__(256) unsigned short ks[2][64 * 64];
    __shared__ __align__(256) unsigned short vts[2][64 * 64];
    __shared__ __align__(16)  unsigned short ps[4][16 * 72];   // padded, per-wave

    const int qt = blockIdx.x, bh = blockIdx.y;
    const int b = bh >> 4, h = bh & 15;
    const int i0 = qt * 64;
    const int tid = threadIdx.x;
    const int w = tid >> 6, lane = tid & 63;
    const int l15 = lane & 15, quad = lane >> 4;

    const unsigned short* Qp = Qb + (size_t)bh * S_LEN * HD;
    const unsigned short* Kp = Kb + (size_t)bh * S_LEN * HD;
    const unsigned short* Vp = VTb + (size_t)bh * HD * S_LEN;

    // stage Q (64 rows x 64 bf16)
    #pragma unroll
    for (int it = 0; it < 2; ++it) {
        int gid = it * 256 + tid;
        int r = gid >> 3, sl = gid & 7;
        int gran = sl ^ (r & 7);
        int wbs = it * 256 + (tid & 192);
        GLOAD_LDS(Qp + (size_t)(i0 + r) * HD + gran * 8, qs + wbs * 8);
    }
    // stage chunk 0
    {
        const int jc0 = i0 - WIN;
        #pragma unroll
        for (int it = 0; it < 2; ++it) {
            int gid = it * 256 + tid;
            int r = gid >> 3, sl = gid & 7;
            int gran = sl ^ (r & 7);
            int wbs = it * 256 + (tid & 192);
            int jg = jc0 + r; jg = jg < 0 ? 0 : (jg > S_LEN - 1 ? S_LEN - 1 : jg);
            GLOAD_LDS(Kp + (size_t)jg * HD + gran * 8, ks[0] + wbs * 8);
            int jc = jc0 + gran * 8; jc = jc < 0 ? 0 : (jc > S_LEN - 8 ? S_LEN - 8 : jc);
            GLOAD_LDS(Vp + (size_t)r * S_LEN + jc, vts[0] + wbs * 8);
        }
    }
    __syncthreads();

    bf16x8 aq[2];
    {
        int row = w * 16 + l15;
        aq[0] = *(const bf16x8*)&qs[(row * 8 + (quad ^ (row & 7))) * 8];
        aq[1] = *(const bf16x8*)&qs[(row * 8 + ((4 + quad) ^ (row & 7))) * 8];
    }
    int jlo4[4], jhi4[4];
    #pragma unroll
    for (int reg = 0; reg < 4; ++reg) {
        int i = i0 + w * 16 + quad * 4 + reg;
        jlo4[reg] = (i - WIN > 0) ? i - WIN : 0;
        jhi4[reg] = (i + WIN < S_LEN) ? i + WIN : S_LEN;
    }
    bf16x8 bones;
    #pragma unroll
    for (int t = 0; t < 8; ++t) bones[t] = (short)0x3F80;   // bf16 1.0

    f32x4 acc_o[4] = {};
    f32x4 acc_sum = {};
    unsigned short* psw = &ps[w][0];

    for (int c = 0; c < 5; ++c) {
        const int cb = c & 1;
        const int jc0 = i0 - WIN + c * 64;

        if (c < 4) {   // overlap next-chunk staging with compute
            const int jn0 = jc0 + 64;
            #pragma unroll
            for (int it = 0; it < 2; ++it) {
                int gid = it * 256 + tid;
                int r = gid >> 3, sl = gid & 7;
                int gran = sl ^ (r & 7);
                int wbs = it * 256 + (tid & 192);
                int jg = jn0 + r; jg = jg < 0 ? 0 : (jg > S_LEN - 1 ? S_LEN - 1 : jg);
                GLOAD_LDS(Kp + (size_t)jg * HD + gran * 8, ks[1 - cb] + wbs * 8);
                int jc = jn0 + gran * 8; jc = jc < 0 ? 0 : (jc > S_LEN - 8 ? S_LEN - 8 : jc);
                GLOAD_LDS(Vp + (size_t)r * S_LEN + jc, vts[1 - cb] + wbs * 8);
            }
        }

        // ---- QK^T: scores[16 q][64 j] ----
        f32x4 sacc[4] = {};
        const unsigned short* kb = ks[cb];
        #pragma unroll
        for (int kk = 0; kk < 2; ++kk) {
            #pragma unroll
            for (int jt = 0; jt < 4; ++jt) {
                int row = jt * 16 + l15;
                bf16x8 bk = *(const bf16x8*)&kb[(row * 8 + ((kk * 4 + quad) ^ (row & 7))) * 8];
                sacc[jt] = __builtin_amdgcn_mfma_f32_16x16x32_bf16(aq[kk], bk, sacc[jt], 0, 0, 0);
            }
        }

        // ---- p'' = valid ? e^{s/8}-1 : 0, C-layout -> LDS -> A-layout ----
        #pragma unroll
        for (int jt = 0; jt < 4; ++jt) {
            int jg = jc0 + jt * 16 + l15;
            #pragma unroll
            for (int reg = 0; reg < 4; ++reg) {
                bool valid = (jg >= jlo4[reg]) && (jg < jhi4[reg]);
                float p = valid ? __expf(sacc[jt][reg] * 0.125f) - 1.f : 0.f;
                psw[(quad * 4 + reg) * 72 + jt * 16 + l15] = f2bf(p);
            }
        }
        bf16x8 ap0 = *(const bf16x8*)&psw[l15 * 72 + quad * 8];
        bf16x8 ap1 = *(const bf16x8*)&psw[l15 * 72 + 32 + quad * 8];

        // ---- PV + row-sum (ones trick) ----
        const unsigned short* vb = vts[cb];
        #pragma unroll
        for (int kst = 0; kst < 2; ++kst) {
            bf16x8 ap = kst ? ap1 : ap0;
            #pragma unroll
            for (int dt = 0; dt < 4; ++dt) {
                int row = dt * 16 + l15;
                bf16x8 bv_ = *(const bf16x8*)&vb[(row * 8 + ((kst * 4 + quad) ^ (row & 7))) * 8];
                acc_o[dt] = __builtin_amdgcn_mfma_f32_16x16x32_bf16(ap, bv_, acc_o[dt], 0, 0, 0);
            }
            acc_sum = __builtin_amdgcn_mfma_f32_16x16x32_bf16(ap, bones, acc_sum, 0, 0, 0);
        }
        __syncthreads();   // drains staging (vmcnt) + buffer-reuse safety
    }

    // ---- epilogue ----
    const float* vtp = vtot + bh * HD;
    float vtv[4];
    #pragma unroll
    for (int dt = 0; dt < 4; ++dt) vtv[dt] = vtp[dt * 16 + l15];
    #pragma unroll
    for (int reg = 0; reg < 4; ++reg) {
        int i = i0 + w * 16 + quad * 4 + reg;
        float inv = 1.f / (acc_sum[reg] + (float)S_LEN);
        float* op = out + (((size_t)(b * S_LEN + i)) * NHEAD + h) * HD;
        #pragma unroll
        for (int dt = 0; dt < 4; ++dt)
            op[dt * 16 + l15] = (acc_o[dt][reg] + vtv[dt]) * inv;
    }
}

extern "C" void kernel_launch(void* const* d_in, const int* in_sizes, int n_in,
                              void* d_out, int out_size, void* d_ws, size_t ws_size,
                              hipStream_t stream)
{
    const float* x  = (const float*)d_in[0];
    const float* Wq = (const float*)d_in[1];
    const float* bq = (const float*)d_in[2];
    const float* Wk = (const float*)d_in[3];
    const float* bk = (const float*)d_in[4];
    const float* Wv = (const float*)d_in[5];
    const float* bv = (const float*)d_in[6];
    float* out = (float*)d_out;

    const size_t NY = (size_t)MTOT * E_DIM;   // 4194304 elements
    unsigned short* xb  = (unsigned short*)d_ws;
    unsigned short* wb  = xb + NY;                        // 3*E*E = 3145728
    unsigned short* Qb  = wb + (size_t)3 * E_DIM * E_DIM;
    unsigned short* Kb  = Qb + NY;
    unsigned short* Vb  = Kb + NY;
    float* vt = (float*)(Vb + NY);
    unsigned short* VTb = xb;   // alias: xb dead after gemm consumes it

    convert_kernel<<<1792, 256, 0, stream>>>(x, Wq, Wk, Wv, xb, wb);
    gemm_mfma<<<dim3(NMAT / 128, MTOT / 128), 256, 0, stream>>>(xb, wb, bq, bk, bv, Qb, Kb, Vb);
    transpose_v<<<dim3(S_LEN / 64, NB * NHEAD), 256, 0, stream>>>(Vb, VTb);
    vtot_kernel<<<NB * NHEAD, 256, 0, stream>>>(VTb, vt);
    attn_mfma<<<dim3(S_LEN / 64, NB * NHEAD), 256, 0, stream>>>(Qb, Kb, VTb, vt, out);
}

// Round 5
// 152.578 us; speedup vs baseline: 7.0186x; 1.0524x over previous
//
#include <hip/hip_runtime.h>
#include <math.h>

#define S_LEN 2048
#define E_DIM 1024
#define NHEAD 16
#define HD 64
#define WIN 128
#define NB 2
#define MTOT (NB * S_LEN)   // 4096
#define NMAT 3072

typedef float f32x4 __attribute__((ext_vector_type(4)));
typedef short bf16x8 __attribute__((ext_vector_type(8)));

#define GLOAD_LDS(g, l) __builtin_amdgcn_global_load_lds( \
    (const __attribute__((address_space(1))) unsigned int*)(g), \
    (__attribute__((address_space(3))) unsigned int*)(l), 16, 0, 0)

__device__ __forceinline__ unsigned short f2bf(float f) {
    unsigned u = __float_as_uint(f);
    u += 0x7fffu + ((u >> 16) & 1u);   // RNE
    return (unsigned short)(u >> 16);
}
__device__ __forceinline__ float bf2f(unsigned short u) {
    return __uint_as_float(((unsigned)u) << 16);
}

// ---------------- fp32 -> bf16 conversion of x and concat(Wq,Wk,Wv) ----------------
__global__ __launch_bounds__(256) void convert_kernel(
    const float* __restrict__ x, const float* __restrict__ wq,
    const float* __restrict__ wk, const float* __restrict__ wv,
    unsigned short* __restrict__ xb, unsigned short* __restrict__ wb)
{
    const int NXQ = MTOT * E_DIM / 4;      // 1048576 quads
    const int NWQ = E_DIM * E_DIM / 4;     // 262144
    const int TOT = NXQ + 3 * NWQ;         // 1835008
    for (int i = blockIdx.x * 256 + threadIdx.x; i < TOT; i += gridDim.x * 256) {
        const float* src; unsigned short* dst; int off;
        if (i < NXQ)               { src = x;  dst = xb;                     off = i; }
        else if (i < NXQ + NWQ)    { src = wq; dst = wb;                     off = i - NXQ; }
        else if (i < NXQ + 2*NWQ)  { src = wk; dst = wb + E_DIM * E_DIM;     off = i - NXQ - NWQ; }
        else                       { src = wv; dst = wb + 2 * E_DIM * E_DIM; off = i - NXQ - 2*NWQ; }
        float4 v = ((const float4*)src)[off];
        ushort4 o;
        o.x = f2bf(v.x); o.y = f2bf(v.y); o.z = f2bf(v.z); o.w = f2bf(v.w);
        ((ushort4*)dst)[off] = o;
    }
}

// ---------------- bf16 MFMA GEMM: Y[m,n] = bias[n] + sum_k A[m,k]*B[n,k] ----------------
// Epilogue stores Q/K/V in the FAITHFUL reshape layout [bh][i][d]:
//   h = (m&2047)>>7, i = ((m&2047)&127)*16 + (n>>6), d = n&63   (reference view() w/o transpose)
__global__ __launch_bounds__(256) void gemm_mfma(
    const unsigned short* __restrict__ Ab, const unsigned short* __restrict__ Bb,
    const float* __restrict__ bq, const float* __restrict__ bk, const float* __restrict__ bv,
    unsigned short* __restrict__ Qb, unsigned short* __restrict__ Kb,
    unsigned short* __restrict__ Vb)
{
    __shared__ __align__(256) unsigned short As[128 * 64];
    __shared__ __align__(256) unsigned short Bs[128 * 64];
    const int tid  = threadIdx.x;
    const int lane = tid & 63;
    const int w    = tid >> 6;
    const int wm   = w & 1, wn = w >> 1;
    const int m0   = blockIdx.y * 128;
    const int n0   = blockIdx.x * 128;
    const int l15  = lane & 15, l4 = lane >> 4;

    f32x4 acc[16] = {};

    for (int k0 = 0; k0 < E_DIM; k0 += 64) {
        #pragma unroll
        for (int is = 0; is < 4; ++is) {
            int gid = is * 256 + tid;
            int r = gid >> 3, sl = gid & 7;
            int gran = sl ^ (r & 7);             // XOR swizzle (granule = 8 bf16 = 16 B)
            int wbs = is * 256 + (tid & 192);    // wave-uniform LDS base (granules)
            GLOAD_LDS(Ab + (size_t)(m0 + r) * E_DIM + k0 + gran * 8, As + wbs * 8);
            GLOAD_LDS(Bb + (size_t)(n0 + r) * E_DIM + k0 + gran * 8, Bs + wbs * 8);
        }
        __syncthreads();
        #pragma unroll
        for (int kk = 0; kk < 2; ++kk) {
            bf16x8 af[4], bfr[4];
            int sa = (kk * 4 + l4) ^ (l15 & 7);
            #pragma unroll
            for (int t = 0; t < 4; ++t) {
                int ra = wm * 64 + t * 16 + l15;
                af[t]  = *(const bf16x8*)&As[ra * 64 + sa * 8];
                int rb = wn * 64 + t * 16 + l15;
                bfr[t] = *(const bf16x8*)&Bs[rb * 64 + sa * 8];
            }
            #pragma unroll
            for (int mt = 0; mt < 4; ++mt)
                #pragma unroll
                for (int nt = 0; nt < 4; ++nt)
                    acc[mt * 4 + nt] = __builtin_amdgcn_mfma_f32_16x16x32_bf16(
                        af[mt], bfr[nt], acc[mt * 4 + nt], 0, 0, 0);
        }
        __syncthreads();
    }

    const int sel = n0 >> 10;
    const float* bias = (sel == 0) ? bq : ((sel == 1) ? bk : bv);
    unsigned short* Yb = (sel == 0) ? Qb : ((sel == 1) ? Kb : Vb);
    const int nbase = (n0 & 1023) + wn * 64;
    #pragma unroll
    for (int mt = 0; mt < 4; ++mt) {
        #pragma unroll
        for (int nt = 0; nt < 4; ++nt) {
            int n = nbase + nt * 16 + l15;      // e index in [0,1024)
            int c = n >> 6, d = n & 63;
            float bb = bias[n];
            #pragma unroll
            for (int r = 0; r < 4; ++r) {
                int m = m0 + wm * 64 + mt * 16 + l4 * 4 + r;
                int b = m >> 11, s = m & 2047;
                int h = s >> 7;
                int i = ((s & 127) << 4) + c;   // faithful reshape
                Yb[(((size_t)(b * 16 + h) * S_LEN + i) << 6) + d] =
                    f2bf(acc[mt * 4 + nt][r] + bb);
            }
        }
    }
}

// ---------------- fused transpose + column-sum: Vb[bh][i][d] -> VTb[bh][d][i], vt += colsum ----------------
__global__ __launch_bounds__(256) void transpose_vtot(
    const unsigned short* __restrict__ Vb, unsigned short* __restrict__ VTb,
    float* __restrict__ vt)
{
    __shared__ unsigned short t[64][72];
    const int bh = blockIdx.y;
    const int it0 = blockIdx.x * 64;
    const int tid = threadIdx.x;
    const unsigned short* src = Vb + ((size_t)bh * S_LEN + it0) * HD;
    {
        int r = tid >> 2, c0 = (tid & 3) * 16;
        #pragma unroll
        for (int k = 0; k < 4; ++k) {
            ushort4 a = *(const ushort4*)&src[r * 64 + c0 + k * 4];
            *(ushort4*)&t[r][c0 + k * 4] = a;
        }
    }
    __syncthreads();
    {
        int d = tid >> 2, seg = (tid & 3) * 16;
        unsigned short v[16];
        float s = 0.f;
        #pragma unroll
        for (int k = 0; k < 16; ++k) { v[k] = t[seg + k][d]; s += bf2f(v[k]); }
        unsigned short* dst = VTb + ((size_t)bh * HD + d) * S_LEN + it0 + seg;
        #pragma unroll
        for (int k = 0; k < 4; ++k)
            *(ushort4*)&dst[k * 4] = *(const ushort4*)&v[k * 4];
        s += __shfl_xor(s, 1);
        s += __shfl_xor(s, 2);
        if ((tid & 3) == 0) atomicAdd(&vt[bh * HD + d], s);
    }
}

// ---------------- MFMA attention: p'' = win ? e^{s*scale}-1 : 0 ----------------
// out = (sum p'' v + Vtot) / (sum p'' + S).  128-query tile, variable chunk range (no OOB).
__global__ __launch_bounds__(256) void attn_mfma(
    const unsigned short* __restrict__ Qb, const unsigned short* __restrict__ Kb,
    const unsigned short* __restrict__ VTb, const float* __restrict__ vtot,
    float* __restrict__ out)
{
    __shared__ __align__(256) unsigned short qs[128 * 64];
    __shared__ __align__(256) unsigned short ks[2][64 * 64];
    __shared__ __align__(256) unsigned short vts[2][64 * 64];
    __shared__ __align__(16)  unsigned short ps[4][32 * 72];   // per-wave P, padded stride

    const int qt = blockIdx.x, bh = blockIdx.y;
    const int b = bh >> 4, h = bh & 15;
    const int i0 = qt * 128;
    const int tid = threadIdx.x;
    const int w = tid >> 6, lane = tid & 63;
    const int l15 = lane & 15, quad = lane >> 4;

    const unsigned short* Qp = Qb + (size_t)bh * S_LEN * HD;
    const unsigned short* Kp = Kb + (size_t)bh * S_LEN * HD;
    const unsigned short* Vp = VTb + (size_t)bh * HD * S_LEN;

    // stage Q (128 rows x 64 bf16), granule-XOR swizzled
    #pragma unroll
    for (int it = 0; it < 4; ++it) {
        int gid = it * 256 + tid;
        int r = gid >> 3, sl = gid & 7;
        int gran = sl ^ (r & 7);
        int wbs = it * 256 + (tid & 192);
        GLOAD_LDS(Qp + (size_t)(i0 + r) * HD + gran * 8, qs + wbs * 8);
    }

    const int j_begin = (i0 - WIN > 0) ? i0 - WIN : 0;
    const int j_end   = (i0 + 256 < S_LEN) ? i0 + 256 : S_LEN;
    const int n_ch    = (j_end - j_begin) >> 6;   // 4 (edges) or 6

    // stage chunk 0 (all rows in-bounds by construction)
    #pragma unroll
    for (int it = 0; it < 2; ++it) {
        int gid = it * 256 + tid;
        int r = gid >> 3, sl = gid & 7;
        int gran = sl ^ (r & 7);
        int wbs = it * 256 + (tid & 192);
        GLOAD_LDS(Kp + (size_t)(j_begin + r) * HD + gran * 8, ks[0] + wbs * 8);
        GLOAD_LDS(Vp + (size_t)r * S_LEN + j_begin + gran * 8, vts[0] + wbs * 8);
    }
    __syncthreads();

    // Q A-fragments: two 16-row subtiles per wave (rows w*32 .. w*32+31)
    bf16x8 aq[2][2];
    #pragma unroll
    for (int q2 = 0; q2 < 2; ++q2) {
        int row = w * 32 + q2 * 16 + l15;
        aq[q2][0] = *(const bf16x8*)&qs[(row * 8 + (quad ^ (row & 7))) * 8];
        aq[q2][1] = *(const bf16x8*)&qs[(row * 8 + ((4 + quad) ^ (row & 7))) * 8];
    }
    bf16x8 bones;
    #pragma unroll
    for (int t = 0; t < 8; ++t) bones[t] = (short)0x3F80;   // bf16 1.0

    f32x4 acc_o[2][4] = {};
    f32x4 acc_sum[2] = {};
    unsigned short* psw = &ps[w][0];

    for (int c = 0; c < n_ch; ++c) {
        const int cb = c & 1;
        const int jc0 = j_begin + c * 64;

        if (c + 1 < n_ch) {   // overlap next-chunk staging with compute
            const int jn0 = jc0 + 64;
            #pragma unroll
            for (int it = 0; it < 2; ++it) {
                int gid = it * 256 + tid;
                int r = gid >> 3, sl = gid & 7;
                int gran = sl ^ (r & 7);
                int wbs = it * 256 + (tid & 192);
                GLOAD_LDS(Kp + (size_t)(jn0 + r) * HD + gran * 8, ks[1 - cb] + wbs * 8);
                GLOAD_LDS(Vp + (size_t)r * S_LEN + jn0 + gran * 8, vts[1 - cb] + wbs * 8);
            }
        }

        // ---- QK^T: scores[2 x 16 q][64 j] ----
        f32x4 sacc[2][4] = {};
        const unsigned short* kb = ks[cb];
        #pragma unroll
        for (int kk = 0; kk < 2; ++kk) {
            #pragma unroll
            for (int jt = 0; jt < 4; ++jt) {
                int row = jt * 16 + l15;
                bf16x8 bk = *(const bf16x8*)&kb[(row * 8 + ((kk * 4 + quad) ^ (row & 7))) * 8];
                sacc[0][jt] = __builtin_amdgcn_mfma_f32_16x16x32_bf16(aq[0][kk], bk, sacc[0][jt], 0, 0, 0);
                sacc[1][jt] = __builtin_amdgcn_mfma_f32_16x16x32_bf16(aq[1][kk], bk, sacc[1][jt], 0, 0, 0);
            }
        }

        // ---- p'' = in-window ? e^{s/8}-1 : 0 ; C-layout -> LDS -> A-layout (wave-local) ----
        #pragma unroll
        for (int q2 = 0; q2 < 2; ++q2) {
            #pragma unroll
            for (int jt = 0; jt < 4; ++jt) {
                int jg = jc0 + jt * 16 + l15;
                #pragma unroll
                for (int reg = 0; reg < 4; ++reg) {
                    int i = i0 + w * 32 + q2 * 16 + quad * 4 + reg;
                    bool valid = (jg >= i - WIN) && (jg < i + WIN);   // jg always in [0,S)
                    float p = valid ? __expf(sacc[q2][jt][reg] * 0.125f) - 1.f : 0.f;
                    psw[(q2 * 16 + quad * 4 + reg) * 72 + jt * 16 + l15] = f2bf(p);
                }
            }
        }
        bf16x8 ap[2][2];
        #pragma unroll
        for (int q2 = 0; q2 < 2; ++q2) {
            ap[q2][0] = *(const bf16x8*)&psw[(q2 * 16 + l15) * 72 + quad * 8];
            ap[q2][1] = *(const bf16x8*)&psw[(q2 * 16 + l15) * 72 + 32 + quad * 8];
        }

        // ---- PV + row-sum (ones trick) ----
        const unsigned short* vb = vts[cb];
        #pragma unroll
        for (int kst = 0; kst < 2; ++kst) {
            #pragma unroll
            for (int dt = 0; dt < 4; ++dt) {
                int row = dt * 16 + l15;
                bf16x8 bv_ = *(const bf16x8*)&vb[(row * 8 + ((kst * 4 + quad) ^ (row & 7))) * 8];
                acc_o[0][dt] = __builtin_amdgcn_mfma_f32_16x16x32_bf16(ap[0][kst], bv_, acc_o[0][dt], 0, 0, 0);
                acc_o[1][dt] = __builtin_amdgcn_mfma_f32_16x16x32_bf16(ap[1][kst], bv_, acc_o[1][dt], 0, 0, 0);
            }
            acc_sum[0] = __builtin_amdgcn_mfma_f32_16x16x32_bf16(ap[0][kst], bones, acc_sum[0], 0, 0, 0);
            acc_sum[1] = __builtin_amdgcn_mfma_f32_16x16x32_bf16(ap[1][kst], bones, acc_sum[1], 0, 0, 0);
        }
        __syncthreads();   // staging buffer reuse safety (drains vmcnt via barrier semantics)
    }

    // ---- epilogue ----
    const float* vtp = vtot + bh * HD;
    float vtv[4];
    #pragma unroll
    for (int dt = 0; dt < 4; ++dt) vtv[dt] = vtp[dt * 16 + l15];
    #pragma unroll
    for (int q2 = 0; q2 < 2; ++q2) {
        #pragma unroll
        for (int reg = 0; reg < 4; ++reg) {
            int i = i0 + w * 32 + q2 * 16 + quad * 4 + reg;
            float inv = 1.f / (acc_sum[q2][reg] + (float)S_LEN);
            float* op = out + (((size_t)(b * S_LEN + i)) * NHEAD + h) * HD;
            #pragma unroll
            for (int dt = 0; dt < 4; ++dt)
                op[dt * 16 + l15] = (acc_o[q2][dt][reg] + vtv[dt]) * inv;
        }
    }
}

extern "C" void kernel_launch(void* const* d_in, const int* in_sizes, int n_in,
                              void* d_out, int out_size, void* d_ws, size_t ws_size,
                              hipStream_t stream)
{
    const float* x  = (const float*)d_in[0];
    const float* Wq = (const float*)d_in[1];
    const float* bq = (const float*)d_in[2];
    const float* Wk = (const float*)d_in[3];
    const float* bk = (const float*)d_in[4];
    const float* Wv = (const float*)d_in[5];
    const float* bv = (const float*)d_in[6];
    float* out = (float*)d_out;

    const size_t NY = (size_t)MTOT * E_DIM;   // 4194304 elements
    unsigned short* xb  = (unsigned short*)d_ws;
    unsigned short* wb  = xb + NY;                        // 3*E*E = 3145728
    unsigned short* Qb  = wb + (size_t)3 * E_DIM * E_DIM;
    unsigned short* Kb  = Qb + NY;
    unsigned short* Vb  = Kb + NY;
    float* vt = (float*)(Vb + NY);
    unsigned short* VTb = xb;   // alias: xb dead after gemm consumes it

    convert_kernel<<<1792, 256, 0, stream>>>(x, Wq, Wk, Wv, xb, wb);
    gemm_mfma<<<dim3(NMAT / 128, MTOT / 128), 256, 0, stream>>>(xb, wb, bq, bk, bv, Qb, Kb, Vb);
    hipMemsetAsync(vt, 0, (size_t)NB * NHEAD * HD * sizeof(float), stream);
    transpose_vtot<<<dim3(S_LEN / 64, NB * NHEAD), 256, 0, stream>>>(Vb, VTb, vt);
    attn_mfma<<<dim3(S_LEN / 128, NB * NHEAD), 256, 0, stream>>>(Qb, Kb, VTb, vt, out);
}

// Round 6
// 151.408 us; speedup vs baseline: 7.0728x; 1.0077x over previous
//
#include <hip/hip_runtime.h>
#include <math.h>

#define S_LEN 2048
#define E_DIM 1024
#define NHEAD 16
#define HD 64
#define WIN 128
#define NB 2
#define MTOT (NB * S_LEN)   // 4096
#define NMAT 3072

typedef float f32x4 __attribute__((ext_vector_type(4)));
typedef short bf16x8 __attribute__((ext_vector_type(8)));

#define GLOAD_LDS(g, l) __builtin_amdgcn_global_load_lds( \
    (const __attribute__((address_space(1))) unsigned int*)(g), \
    (__attribute__((address_space(3))) unsigned int*)(l), 16, 0, 0)

__device__ __forceinline__ unsigned short f2bf(float f) {
    unsigned u = __float_as_uint(f);
    u += 0x7fffu + ((u >> 16) & 1u);   // RNE
    return (unsigned short)(u >> 16);
}
__device__ __forceinline__ float bf2f(unsigned short u) {
    return __uint_as_float(((unsigned)u) << 16);
}

// ---------------- fp32 -> bf16 conversion of x and concat(Wq,Wk,Wv) ----------------
__global__ __launch_bounds__(256) void convert_kernel(
    const float* __restrict__ x, const float* __restrict__ wq,
    const float* __restrict__ wk, const float* __restrict__ wv,
    unsigned short* __restrict__ xb, unsigned short* __restrict__ wb)
{
    const int NXQ = MTOT * E_DIM / 4;      // 1048576 quads
    const int NWQ = E_DIM * E_DIM / 4;     // 262144
    const int TOT = NXQ + 3 * NWQ;         // 1835008
    for (int i = blockIdx.x * 256 + threadIdx.x; i < TOT; i += gridDim.x * 256) {
        const float* src; unsigned short* dst; int off;
        if (i < NXQ)               { src = x;  dst = xb;                     off = i; }
        else if (i < NXQ + NWQ)    { src = wq; dst = wb;                     off = i - NXQ; }
        else if (i < NXQ + 2*NWQ)  { src = wk; dst = wb + E_DIM * E_DIM;     off = i - NXQ - NWQ; }
        else                       { src = wv; dst = wb + 2 * E_DIM * E_DIM; off = i - NXQ - 2*NWQ; }
        float4 v = ((const float4*)src)[off];
        ushort4 o;
        o.x = f2bf(v.x); o.y = f2bf(v.y); o.z = f2bf(v.z); o.w = f2bf(v.w);
        ((ushort4*)dst)[off] = o;
    }
}

// ---------------- bf16 MFMA GEMM: Y[m,n] = bias[n] + sum_k A[m,k]*B[n,k] ----------------
// Epilogue stores Q/K/V in the FAITHFUL reshape layout [bh][i][d]:
//   h = (m&2047)>>7, i = ((m&2047)&127)*16 + (n>>6), d = n&63   (reference view() w/o transpose)
// For V blocks (sel==2) also accumulates vt[bh][d] = sum_i V[bh][i][d] (fp32, atomics).
__global__ __launch_bounds__(256) void gemm_mfma(
    const unsigned short* __restrict__ Ab, const unsigned short* __restrict__ Bb,
    const float* __restrict__ bq, const float* __restrict__ bk, const float* __restrict__ bv,
    unsigned short* __restrict__ Qb, unsigned short* __restrict__ Kb,
    unsigned short* __restrict__ Vb, float* __restrict__ vt)
{
    __shared__ __align__(256) unsigned short As[128 * 64];
    __shared__ __align__(256) unsigned short Bs[128 * 64];
    const int tid  = threadIdx.x;
    const int lane = tid & 63;
    const int w    = tid >> 6;
    const int wm   = w & 1, wn = w >> 1;
    const int m0   = blockIdx.y * 128;
    const int n0   = blockIdx.x * 128;
    const int l15  = lane & 15, l4 = lane >> 4;

    f32x4 acc[16] = {};

    for (int k0 = 0; k0 < E_DIM; k0 += 64) {
        #pragma unroll
        for (int is = 0; is < 4; ++is) {
            int gid = is * 256 + tid;
            int r = gid >> 3, sl = gid & 7;
            int gran = sl ^ (r & 7);             // XOR swizzle (granule = 8 bf16 = 16 B)
            int wbs = is * 256 + (tid & 192);    // wave-uniform LDS base (granules)
            GLOAD_LDS(Ab + (size_t)(m0 + r) * E_DIM + k0 + gran * 8, As + wbs * 8);
            GLOAD_LDS(Bb + (size_t)(n0 + r) * E_DIM + k0 + gran * 8, Bs + wbs * 8);
        }
        __syncthreads();
        #pragma unroll
        for (int kk = 0; kk < 2; ++kk) {
            bf16x8 af[4], bfr[4];
            int sa = (kk * 4 + l4) ^ (l15 & 7);
            #pragma unroll
            for (int t = 0; t < 4; ++t) {
                int ra = wm * 64 + t * 16 + l15;
                af[t]  = *(const bf16x8*)&As[ra * 64 + sa * 8];
                int rb = wn * 64 + t * 16 + l15;
                bfr[t] = *(const bf16x8*)&Bs[rb * 64 + sa * 8];
            }
            #pragma unroll
            for (int mt = 0; mt < 4; ++mt)
                #pragma unroll
                for (int nt = 0; nt < 4; ++nt)
                    acc[mt * 4 + nt] = __builtin_amdgcn_mfma_f32_16x16x32_bf16(
                        af[mt], bfr[nt], acc[mt * 4 + nt], 0, 0, 0);
        }
        __syncthreads();
    }

    const int sel = n0 >> 10;
    const float* bias = (sel == 0) ? bq : ((sel == 1) ? bk : bv);
    unsigned short* Yb = (sel == 0) ? Qb : ((sel == 1) ? Kb : Vb);
    const int nbase = (n0 & 1023) + wn * 64;
    #pragma unroll
    for (int mt = 0; mt < 4; ++mt) {
        #pragma unroll
        for (int nt = 0; nt < 4; ++nt) {
            int n = nbase + nt * 16 + l15;      // e index in [0,1024)
            int c = n >> 6, d = n & 63;
            float bb = bias[n];
            #pragma unroll
            for (int r = 0; r < 4; ++r) {
                int m = m0 + wm * 64 + mt * 16 + l4 * 4 + r;
                int b = m >> 11, s = m & 2047;
                int h = s >> 7;
                int i = ((s & 127) << 4) + c;   // faithful reshape
                Yb[(((size_t)(b * 16 + h) * S_LEN + i) << 6) + d] =
                    f2bf(acc[mt * 4 + nt][r] + bb);
            }
        }
    }

    if (sel == 2) {
        // vt[bh][d] += sum over this block's i-values (one m-block == one bh exactly)
        const int bh = (m0 >> 11) * 16 + ((m0 & 2047) >> 7);
        #pragma unroll
        for (int nt = 0; nt < 4; ++nt) {
            float s = 0.f;
            #pragma unroll
            for (int mt = 0; mt < 4; ++mt)
                #pragma unroll
                for (int r = 0; r < 4; ++r) s += acc[mt * 4 + nt][r];
            s += __shfl_xor(s, 16);
            s += __shfl_xor(s, 32);
            if (l4 == 0) {
                int n = nbase + nt * 16 + l15;
                // bias appears once per (block, n): 128 i-rows worth, added by wm==0 wave only
                float add = s + ((wm == 0) ? 128.f * bias[n] : 0.f);
                atomicAdd(&vt[bh * HD + (n & 63)], add);
            }
        }
    }
}

// ---------------- MFMA attention: p'' = win ? e^{s*scale}-1 : 0 ----------------
// out = (sum p'' v + Vtot) / (sum p'' + S).  128-query tile; V transposed in-LDS per chunk.
__global__ __launch_bounds__(256) void attn_mfma(
    const unsigned short* __restrict__ Qb, const unsigned short* __restrict__ Kb,
    const unsigned short* __restrict__ Vb, const float* __restrict__ vtot,
    float* __restrict__ out)
{
    // qps: qs[128*64] (staging, dead after frag extract) UNION ps[4][32*72] (P scratch)
    __shared__ __align__(256) unsigned short qps[9216];
    __shared__ __align__(256) unsigned short ks[2][64 * 64];
    __shared__ __align__(256) unsigned short vts[64 * 64];    // V^T, written by ds_write
    __shared__ __align__(256) unsigned short vscr[64 * 64];   // V rows [j][d], DMA target

    const int qt = blockIdx.x, bh = blockIdx.y;
    const int b = bh >> 4, h = bh & 15;
    const int i0 = qt * 128;
    const int tid = threadIdx.x;
    const int w = tid >> 6, lane = tid & 63;
    const int l15 = lane & 15, quad = lane >> 4;

    const unsigned short* Qp = Qb + (size_t)bh * S_LEN * HD;
    const unsigned short* Kp = Kb + (size_t)bh * S_LEN * HD;
    const unsigned short* Vp = Vb + (size_t)bh * S_LEN * HD;

    // stage Q (128 rows x 64 bf16), granule-XOR swizzled
    #pragma unroll
    for (int it = 0; it < 4; ++it) {
        int gid = it * 256 + tid;
        int r = gid >> 3, sl = gid & 7;
        int gran = sl ^ (r & 7);
        int wbs = it * 256 + (tid & 192);
        GLOAD_LDS(Qp + (size_t)(i0 + r) * HD + gran * 8, qps + wbs * 8);
    }

    const int j_begin = (i0 - WIN > 0) ? i0 - WIN : 0;
    const int j_end   = (i0 + 256 < S_LEN) ? i0 + 256 : S_LEN;
    const int n_ch    = (j_end - j_begin) >> 6;   // 4 (edges) or 6

    // stage chunk 0: K rows -> ks[0], V rows -> vscr (all in-bounds by construction)
    #pragma unroll
    for (int it = 0; it < 2; ++it) {
        int gid = it * 256 + tid;
        int r = gid >> 3, sl = gid & 7;
        int gran = sl ^ (r & 7);
        int wbs = it * 256 + (tid & 192);
        GLOAD_LDS(Kp + (size_t)(j_begin + r) * HD + gran * 8, ks[0] + wbs * 8);
        GLOAD_LDS(Vp + (size_t)(j_begin + r) * HD + gran * 8, vscr + wbs * 8);
    }
    __syncthreads();

    // Q A-fragments: two 16-row subtiles per wave (rows w*32 .. w*32+31)
    bf16x8 aq[2][2];
    #pragma unroll
    for (int q2 = 0; q2 < 2; ++q2) {
        int row = w * 32 + q2 * 16 + l15;
        aq[q2][0] = *(const bf16x8*)&qps[(row * 8 + (quad ^ (row & 7))) * 8];
        aq[q2][1] = *(const bf16x8*)&qps[(row * 8 + ((4 + quad) ^ (row & 7))) * 8];
    }
    bf16x8 bones;
    #pragma unroll
    for (int t = 0; t < 8; ++t) bones[t] = (short)0x3F80;   // bf16 1.0

    f32x4 acc_o[2][4] = {};
    f32x4 acc_sum[2] = {};
    unsigned short* psw = qps + w * 2304;   // per-wave P scratch, 32 rows x stride 72

    const int td = tid & 63;     // d for transpose
    const int toct = tid >> 6;   // j-octet base

    for (int c = 0; c < n_ch; ++c) {
        const int cb = c & 1;
        const int jc0 = j_begin + c * 64;

        // ---- in-LDS transpose: vscr[j][d] -> vts[d][j] (granule-XOR swizzled rows) ----
        #pragma unroll
        for (int pc = 0; pc < 2; ++pc) {
            int oct = toct + pc * 4;
            bf16x8 vv;
            #pragma unroll
            for (int t = 0; t < 8; ++t)
                vv[t] = (short)vscr[(oct * 8 + t) * 64 + (((td >> 3) ^ t) * 8) + (td & 7)];
            *(bf16x8*)&vts[td * 64 + ((oct ^ (td & 7)) * 8)] = vv;
        }
        __syncthreads();   // vts visible; vscr free for next DMA

        if (c + 1 < n_ch) {   // prefetch next chunk, overlapped with QK/exp/PV below
            const int jn0 = jc0 + 64;
            #pragma unroll
            for (int it = 0; it < 2; ++it) {
                int gid = it * 256 + tid;
                int r = gid >> 3, sl = gid & 7;
                int gran = sl ^ (r & 7);
                int wbs = it * 256 + (tid & 192);
                GLOAD_LDS(Kp + (size_t)(jn0 + r) * HD + gran * 8, ks[1 - cb] + wbs * 8);
                GLOAD_LDS(Vp + (size_t)(jn0 + r) * HD + gran * 8, vscr + wbs * 8);
            }
        }

        // ---- QK^T: scores[2 x 16 q][64 j] ----
        f32x4 sacc[2][4] = {};
        const unsigned short* kb = ks[cb];
        #pragma unroll
        for (int kk = 0; kk < 2; ++kk) {
            #pragma unroll
            for (int jt = 0; jt < 4; ++jt) {
                int row = jt * 16 + l15;
                bf16x8 bk = *(const bf16x8*)&kb[(row * 8 + ((kk * 4 + quad) ^ (row & 7))) * 8];
                sacc[0][jt] = __builtin_amdgcn_mfma_f32_16x16x32_bf16(aq[0][kk], bk, sacc[0][jt], 0, 0, 0);
                sacc[1][jt] = __builtin_amdgcn_mfma_f32_16x16x32_bf16(aq[1][kk], bk, sacc[1][jt], 0, 0, 0);
            }
        }

        // ---- p'' = in-window ? e^{s/8}-1 : 0 ; C-layout -> LDS -> A-layout (wave-local) ----
        #pragma unroll
        for (int q2 = 0; q2 < 2; ++q2) {
            #pragma unroll
            for (int jt = 0; jt < 4; ++jt) {
                int jg = jc0 + jt * 16 + l15;
                #pragma unroll
                for (int reg = 0; reg < 4; ++reg) {
                    int i = i0 + w * 32 + q2 * 16 + quad * 4 + reg;
                    bool valid = (jg >= i - WIN) && (jg < i + WIN);   // jg always in [0,S)
                    float p = valid ? __expf(sacc[q2][jt][reg] * 0.125f) - 1.f : 0.f;
                    psw[(q2 * 16 + quad * 4 + reg) * 72 + jt * 16 + l15] = f2bf(p);
                }
            }
        }
        bf16x8 ap[2][2];
        #pragma unroll
        for (int q2 = 0; q2 < 2; ++q2) {
            ap[q2][0] = *(const bf16x8*)&psw[(q2 * 16 + l15) * 72 + quad * 8];
            ap[q2][1] = *(const bf16x8*)&psw[(q2 * 16 + l15) * 72 + 32 + quad * 8];
        }

        // ---- PV + row-sum (ones trick) ----
        #pragma unroll
        for (int kst = 0; kst < 2; ++kst) {
            #pragma unroll
            for (int dt = 0; dt < 4; ++dt) {
                int row = dt * 16 + l15;
                bf16x8 bv_ = *(const bf16x8*)&vts[(row * 8 + ((kst * 4 + quad) ^ (row & 7))) * 8];
                acc_o[0][dt] = __builtin_amdgcn_mfma_f32_16x16x32_bf16(ap[0][kst], bv_, acc_o[0][dt], 0, 0, 0);
                acc_o[1][dt] = __builtin_amdgcn_mfma_f32_16x16x32_bf16(ap[1][kst], bv_, acc_o[1][dt], 0, 0, 0);
            }
            acc_sum[0] = __builtin_amdgcn_mfma_f32_16x16x32_bf16(ap[0][kst], bones, acc_sum[0], 0, 0, 0);
            acc_sum[1] = __builtin_amdgcn_mfma_f32_16x16x32_bf16(ap[1][kst], bones, acc_sum[1], 0, 0, 0);
        }
        __syncthreads();   // drains this chunk's DMA; protects ks/vts reuse
    }

    // ---- epilogue ----
    const float* vtp = vtot + bh * HD;
    float vtv[4];
    #pragma unroll
    for (int dt = 0; dt < 4; ++dt) vtv[dt] = vtp[dt * 16 + l15];
    #pragma unroll
    for (int q2 = 0; q2 < 2; ++q2) {
        #pragma unroll
        for (int reg = 0; reg < 4; ++reg) {
            int i = i0 + w * 32 + q2 * 16 + quad * 4 + reg;
            float inv = 1.f / (acc_sum[q2][reg] + (float)S_LEN);
            float* op = out + (((size_t)(b * S_LEN + i)) * NHEAD + h) * HD;
            #pragma unroll
            for (int dt = 0; dt < 4; ++dt)
                op[dt * 16 + l15] = (acc_o[q2][dt][reg] + vtv[dt]) * inv;
        }
    }
}

extern "C" void kernel_launch(void* const* d_in, const int* in_sizes, int n_in,
                              void* d_out, int out_size, void* d_ws, size_t ws_size,
                              hipStream_t stream)
{
    const float* x  = (const float*)d_in[0];
    const float* Wq = (const float*)d_in[1];
    const float* bq = (const float*)d_in[2];
    const float* Wk = (const float*)d_in[3];
    const float* bk = (const float*)d_in[4];
    const float* Wv = (const float*)d_in[5];
    const float* bv = (const float*)d_in[6];
    float* out = (float*)d_out;

    const size_t NY = (size_t)MTOT * E_DIM;   // 4194304 elements
    unsigned short* xb  = (unsigned short*)d_ws;
    unsigned short* wb  = xb + NY;                        // 3*E*E = 3145728
    unsigned short* Qb  = wb + (size_t)3 * E_DIM * E_DIM;
    unsigned short* Kb  = Qb + NY;
    unsigned short* Vb  = Kb + NY;
    float* vt = (float*)(Vb + NY);                        // 32*64 fp32

    convert_kernel<<<1792, 256, 0, stream>>>(x, Wq, Wk, Wv, xb, wb);
    hipMemsetAsync(vt, 0, (size_t)NB * NHEAD * HD * sizeof(float), stream);
    gemm_mfma<<<dim3(NMAT / 128, MTOT / 128), 256, 0, stream>>>(xb, wb, bq, bk, bv, Qb, Kb, Vb, vt);
    attn_mfma<<<dim3(S_LEN / 128, NB * NHEAD), 256, 0, stream>>>(Qb, Kb, Vb, vt, out);
}